// Round 18
// baseline (329.479 us; speedup 1.0000x reference)
//
#include <hip/hip_runtime.h>

// VQ-VAE vector quantizer, MI355X — MFMA screen (16x16x32, E-resident 64 VGPR,
// 8 chains/wave, 3 waves/SIMD, free-running, 64-strip partials) + exact refine.
// z: (4,256,16,32,32) f32 ; emb: (1024,256) f32
// out (f32): z_q_st[16777216] | vq_loss | perplexity | indices[65536]
//
// Exactness contract (validated rounds 2-17, absmax 0):
//   x_sq[n], e_sq[k]: numpy pairwise sum of fl32(v*v) (two 128-blocks, 8 accs)
//   xe[n][k]: single sequential f32 FMA chain over c=0..255
//   d = fl32( fl32(x_sq+e_sq) - 2*xe ), argmin first-min tie-break.
// Screen: bf16-split MFMA eh*zh + el*zh, ranked xs-free by (esq - 2*dot)
// (validated r17); merged gap <= T_GAP=6e-4 -> bit-exact scalar-chain refine.
// pm gap is floor-quantized to u16*1e-6 (decode <= true gap -> flags only
// increase, never decrease).
//
// Round-18: r12-r17 ledger: MfmaUtil pinned 19-38%, best (38%) at the most
// accumulator chains per SIMD (r13: 8x2). Wall = MFMA dependent latency x
// chain count x waves, with 2 waves/SIMD forced by 32x32's 128-VGPR E.
// Switch to 16x16x32: E = 64 VGPR (16-k strip), acc 8 chains x 4 = 32,
// ~140 VGPR -> 3 waves/SIMD x 8 chains = 24 chains/SIMD. Free-running waves
// (no LDS/barriers, r17-validated), 64 k-strips, 8 B/entry packed partials.

#define C_DIM 256
#define K_CODES 1024
#define N_VEC 65536
#define T_GAP 6e-4f

#define OUT_ZQ_SIZE 16777216
#define OUT_LOSS_OFF 16777216
#define OUT_PP_OFF   16777217
#define OUT_IDX_OFF  16777218

// ws layout (bytes)
#define WS_EH    0          // bf16 frag16-major [64 kt][8 q][64 l][8]   512 KB
#define WS_EL    524288     // same                                      512 KB
#define WS_ESQ   1048576    // f32 [1024]
#define WS_XSQ   1052672    // f32 [65536]  (refine only)
#define WS_CNT   1314816    // u32 counts[1024]
#define WS_LOSS  1318912    // f64 loss
#define WS_FLC   1318920    // u32 flag count
#define WS_FLIST 1581072    // u32 flag_list[65536]
#define WS_EMBT  1843264    // f32 [256][1024]  (ends 2891840)

// pm partials in the free zlF half of out (floats [8388608,16777216)):
//   pmA   f32[64][65536]  (16 MB)
//   packd u32[64][65536]  (16 MB): (idx u16 << 16) | gap_q u16 (gap*1e6, floor)

typedef __attribute__((ext_vector_type(8))) short short8;
typedef __attribute__((ext_vector_type(8))) unsigned short ushort8;
typedef __attribute__((ext_vector_type(4))) float f32x4;

__device__ __forceinline__ unsigned short bf16_rne(float v) {
    unsigned u = __float_as_uint(v);
    unsigned r = (u + 0x7FFFu + ((u >> 16) & 1u)) >> 16;
    return (unsigned short)r;
}

// frag16-major address (shorts) of element (row, c) in a panel of 16-row tiles:
//   off = (row>>4)*4096 + (c>>5)*512 + ((row&15) + 16*((c>>3)&3))*8 + (c&7)
// Both A-operand (rows=k) and B-operand (rows=n) of 16x16x32 use this form:
//   lane l reads chunk[l][j] = elem(row = base + (l&15), c = c0 + (l>>4)*8 + j)

// ---------- conversions (xsq fused into convert_z; esq fused into convert_e) ----------

__global__ __launch_bounds__(256) void convert_z_kernel(const float* __restrict__ z,
                                                        unsigned short* __restrict__ zhF,
                                                        float* __restrict__ xsq) {
#pragma clang fp contract(off)
    __shared__ float tile[128][65];
    const int tid = threadIdx.x;
    const int ln = tid & 63;
    const int og = tid >> 6;
    const int n0 = blockIdx.x * 64;
    const int b = n0 >> 14, s0 = n0 & 16383;
    const int n = n0 + ln;
    float res = 0.0f;

    for (int p = 0; p < 2; ++p) {
        __syncthreads();
        for (int i = 0; i < 32; ++i) {
            int c = p * 128 + i * 4 + og;
            tile[i * 4 + og][ln] = z[((size_t)b << 22) + ((size_t)c << 14) + s0 + ln];
        }
        __syncthreads();
#pragma unroll
        for (int t = 0; t < 4; ++t) {
            int oh = og + t * 4;               // octet within half, 0..15
            int o  = p * 16 + oh;              // global c-octet 0..31
            ushort8 hb;
#pragma unroll
            for (int j = 0; j < 8; ++j)
                hb[j] = bf16_rne(tile[oh * 8 + j][ln]);
            size_t off = ((size_t)(n >> 4) * 8 + (o >> 2)) * 512
                       + (size_t)((n & 15) + 16 * (o & 3)) * 8;
            *reinterpret_cast<ushort8*>(zhF + off) = hb;
        }
        if (tid < 64) {
            float r[8];
#pragma unroll
            for (int j = 0; j < 8; ++j) { float v = tile[j][tid]; r[j] = v * v; }
#pragma unroll
            for (int i = 8; i < 128; i += 8)
#pragma unroll
                for (int j = 0; j < 8; ++j) { float v = tile[i + j][tid]; float t2 = v * v; r[j] = r[j] + t2; }
            float blk = ((r[0] + r[1]) + (r[2] + r[3])) + ((r[4] + r[5]) + (r[6] + r[7]));
            res = (p == 0) ? blk : res + blk;
        }
    }
    if (tid < 64) xsq[n0 + tid] = res;
}

__device__ __forceinline__ float pairwise_sq_128(const float* p) {
#pragma clang fp contract(off)
    float r[8];
#pragma unroll
    for (int j = 0; j < 8; ++j) { float v = p[j]; r[j] = v * v; }
#pragma unroll
    for (int i = 8; i < 128; i += 8)
#pragma unroll
        for (int j = 0; j < 8; ++j) { float v = p[i + j]; float t = v * v; r[j] = r[j] + t; }
    return ((r[0] + r[1]) + (r[2] + r[3])) + ((r[4] + r[5]) + (r[6] + r[7]));
}

__global__ __launch_bounds__(256) void convert_e_kernel(const float* __restrict__ emb,
                                                        unsigned short* __restrict__ ehF,
                                                        unsigned short* __restrict__ elF,
                                                        float* __restrict__ esq) {
#pragma clang fp contract(off)
    int t = blockIdx.x * 256 + threadIdx.x;   // 32768 threads
    int k = t >> 5, o = t & 31;
    int c0 = o * 8;
    ushort8 hb, lb;
#pragma unroll
    for (int j = 0; j < 8; ++j) {
        float v = emb[k * C_DIM + c0 + j];
        unsigned short h = bf16_rne(v);
        hb[j] = h;
        lb[j] = bf16_rne(v - __uint_as_float((unsigned)h << 16));
    }
    size_t off = ((size_t)(k >> 4) * 8 + (o >> 2)) * 512
               + (size_t)((k & 15) + 16 * (o & 3)) * 8;
    *reinterpret_cast<ushort8*>(ehF + off) = hb;
    *reinterpret_cast<ushort8*>(elF + off) = lb;
    if (threadIdx.x < 8) {
        int k8 = blockIdx.x * 8 + threadIdx.x;
        const float* row = emb + (size_t)k8 * C_DIM;
        esq[k8] = pairwise_sq_128(row) + pairwise_sq_128(row + 128);
    }
}

__global__ __launch_bounds__(256) void transpose_kernel(const float* __restrict__ emb,
                                                        float* __restrict__ embT) {
    __shared__ float t[64][65];
    const int k0 = blockIdx.x * 64;
    const int c0 = blockIdx.y * 64;
    const int tx = threadIdx.x & 63, ty = threadIdx.x >> 6;
    for (int r = ty; r < 64; r += 4)
        t[r][tx] = emb[(k0 + r) * C_DIM + c0 + tx];
    __syncthreads();
    for (int r = ty; r < 64; r += 4)
        embT[(c0 + r) * K_CODES + k0 + tx] = t[tx][r];
}

// ---------- MFMA screen: 16x16x32, free-running waves, 64-strip partials ----------
// block: 256 threads = 4 waves; grid 1024 = 64 ng x 16 sg (XCD-swizzled).
// Wave w: k-strip ks = sg*4 + w (16 k); n-range ng*1024, 16 windows of 64 n.
// Per window: 4 n-tiles; per q (8): 4 B-frag loads + 8 MFMAs into 8 chains.

__global__ __launch_bounds__(256, 3) void screen_kernel(
    const unsigned short* __restrict__ zhF,
    const unsigned short* __restrict__ ehF, const unsigned short* __restrict__ elF,
    const float* __restrict__ esq,
    float* __restrict__ pmA, unsigned* __restrict__ packd) {
    const int tid = threadIdx.x;
    const int w = tid >> 6, l = tid & 63;
    const int bid = blockIdx.x;
    const int v = (bid & 7) * 128 + (bid >> 3);   // XCD-chunked bijective (1024 = 8*128)
    const int ng = v >> 4, sg = v & 15;
    const int ks = sg * 4 + w;                    // k-strip 0..63 (16 k each)
    const int n0 = ng * 1024;
    const int loff = l * 8;

    // resident E: Eh[8], El[8] (frag16 chunks of strip ks)
    short8 Eh[8], El[8];
    {
        const unsigned short* bh = ehF + (size_t)ks * 4096 + loff;
        const unsigned short* bl = elF + (size_t)ks * 4096 + loff;
#pragma unroll
        for (int q = 0; q < 8; ++q) {
            Eh[q] = *reinterpret_cast<const short8*>(bh + q * 512);
            El[q] = *reinterpret_cast<const short8*>(bl + q * 512);
        }
    }
    // per-lane e_sq for the 4 k-rows this lane's acc holds: k = ks*16 + (l>>4)*4 + r
    float esql[4];
#pragma unroll
    for (int r = 0; r < 4; ++r)
        esql[r] = esq[ks * 16 + (l >> 4) * 4 + r];

    for (int s = 0; s < 16; ++s) {
        const int tb = ng * 64 + s * 4;           // first n-tile index of window
        const unsigned short* zb = zhF + (size_t)tb * 4096 + loff;

        f32x4 aH[4], aL[4];
#pragma unroll
        for (int t = 0; t < 4; ++t)
#pragma unroll
            for (int r = 0; r < 4; ++r) { aH[t][r] = 0.0f; aL[t][r] = 0.0f; }

#pragma unroll
        for (int q = 0; q < 8; ++q) {
            short8 zf[4];
#pragma unroll
            for (int t = 0; t < 4; ++t)
                zf[t] = *reinterpret_cast<const short8*>(zb + (size_t)t * 4096 + q * 512);
#pragma unroll
            for (int t = 0; t < 4; ++t)
                aH[t] = __builtin_amdgcn_mfma_f32_16x16x32_bf16(Eh[q], zf[t], aH[t], 0, 0, 0);
#pragma unroll
            for (int t = 0; t < 4; ++t)
                aL[t] = __builtin_amdgcn_mfma_f32_16x16x32_bf16(El[q], zf[t], aL[t], 0, 0, 0);
        }

        // fold per tile: lane's col n = (l&15); 4 k-rows in regs; then butterfly
        // over the 4 lane-groups (disjoint k quarters) at offsets 16, 32.
        float fm1[4], fm2[4];
        int   fi1[4];
#pragma unroll
        for (int t = 0; t < 4; ++t) {
            float m1 = 3.4e38f, m2 = 3.4e38f;
            int i1 = 0;
#pragma unroll
            for (int r = 0; r < 4; ++r) {          // kg ascending in r
                float dot = aH[t][r] + aL[t][r];
                float sv = esql[r] - 2.0f * dot;
                int kg = ks * 16 + (l >> 4) * 4 + r;
                if (sv < m1) { m2 = m1; m1 = sv; i1 = kg; }
                else m2 = fminf(m2, sv);
            }
#pragma unroll
            for (int off = 16; off <= 32; off <<= 1) {
                float om1 = __shfl_xor(m1, off, 64);
                float om2 = __shfl_xor(m2, off, 64);
                int   oi  = __shfl_xor(i1, off, 64);
                if (om1 < m1)      { m2 = fminf(m1, om2); m1 = om1; i1 = oi; }
                else if (om1 > m1) { m2 = fminf(m2, om1); }
                else               { m2 = m1; i1 = min(i1, oi); }
            }
            fm1[t] = m1; fm2[t] = m2; fi1[t] = i1;
        }
        // lane l stores n = w_n0 + l; needs tile t = l>>4 (constant-index select)
        float m1s = (l & 32) ? ((l & 16) ? fm1[3] : fm1[2]) : ((l & 16) ? fm1[1] : fm1[0]);
        float m2s = (l & 32) ? ((l & 16) ? fm2[3] : fm2[2]) : ((l & 16) ? fm2[1] : fm2[0]);
        int   i1s = (l & 32) ? ((l & 16) ? fi1[3] : fi1[2]) : ((l & 16) ? fi1[1] : fi1[0]);

        float gap = m2s - m1s;
        unsigned gq = (unsigned)fminf(floorf(fmaxf(gap, 0.0f) * 1e6f), 65535.0f);
        size_t p = (size_t)ks * N_VEC + n0 + s * 64 + l;
        pmA[p]   = m1s;
        packd[p] = ((unsigned)i1s << 16) | gq;
    }
}

// merge + emit fused: 64-strip reduce; unflagged rows finalized, flagged -> refine
__global__ __launch_bounds__(256) void merge_kernel(
    const float* __restrict__ pmA, const unsigned* __restrict__ packd,
    unsigned* __restrict__ flag_list, unsigned* __restrict__ flag_count,
    float* __restrict__ out_idx, unsigned* __restrict__ counts) {
    int n = blockIdx.x * 256 + threadIdx.x;
    float m1 = 3.4e38f, m2 = 3.4e38f;
    int i1 = 0;
    for (int ks = 0; ks < 64; ++ks) {   // ascending k
        size_t p = (size_t)ks * N_VEC + n;
        float a1 = pmA[p];
        unsigned pk = packd[p];
        int ai = (int)(pk >> 16);
        float a2 = a1 + (float)(pk & 0xFFFFu) * 1e-6f;   // floor-decoded (<= true)
        if (a1 < m1)      { m2 = fminf(m1, a2); m1 = a1; i1 = ai; }
        else if (a1 > m1) { m2 = fminf(m2, a1); }
        else              { m2 = m1; i1 = min(i1, ai); }
    }
    if (m2 - m1 <= T_GAP) {
        unsigned pos = atomicAdd(flag_count, 1u);
        flag_list[pos] = (unsigned)n;
    } else {
        out_idx[n] = (float)i1;
        atomicAdd(&counts[i1], 1u);
    }
}

// ---------- exact-chain refine of flagged rows (8 rows/group) ----------

__global__ __launch_bounds__(256) void refine_kernel(
    const float* __restrict__ z, const float* __restrict__ embT,
    const float* __restrict__ esq, const float* __restrict__ xsq,
    const unsigned* __restrict__ flag_list, const unsigned* __restrict__ flag_count,
    float* __restrict__ out_idx, unsigned* __restrict__ counts) {
#pragma clang fp contract(off)
    __shared__ float zrow[8][256];
    __shared__ int nrow[8];
    __shared__ unsigned long long red[8][4];
    const int tid = threadIdx.x;
    const unsigned cnt = *flag_count;
    const unsigned groups = (cnt + 7) >> 3;
    const int kbase = tid * 4;
    for (unsigned g = blockIdx.x; g < groups; g += gridDim.x) {
        __syncthreads();
        if (tid < 8) nrow[tid] = (g * 8 + tid < cnt) ? (int)flag_list[g * 8 + tid] : -1;
        __syncthreads();
        for (int r = 0; r < 8; ++r) {
            int n = nrow[r];
            if (n >= 0) {
                int b = n >> 14, s = n & 16383;
                zrow[r][tid] = z[((size_t)b << 22) + ((size_t)tid << 14) + s];
            }
        }
        __syncthreads();
        float acc[8][4];
#pragma unroll
        for (int r = 0; r < 8; ++r)
#pragma unroll
            for (int j = 0; j < 4; ++j) acc[r][j] = 0.0f;
        for (int c4 = 0; c4 < 64; ++c4) {
            float4 ek[4];
#pragma unroll
            for (int x = 0; x < 4; ++x)
                ek[x] = *reinterpret_cast<const float4*>(embT + (size_t)(c4 * 4 + x) * K_CODES + kbase);
#pragma unroll
            for (int r = 0; r < 8; ++r) {
                float4 zv = *reinterpret_cast<const float4*>(&zrow[r][c4 * 4]);
                float a;
                a = acc[r][0];
                a = fmaf(zv.x, ek[0].x, a); a = fmaf(zv.y, ek[1].x, a);
                a = fmaf(zv.z, ek[2].x, a); a = fmaf(zv.w, ek[3].x, a);
                acc[r][0] = a;
                a = acc[r][1];
                a = fmaf(zv.x, ek[0].y, a); a = fmaf(zv.y, ek[1].y, a);
                a = fmaf(zv.z, ek[2].y, a); a = fmaf(zv.w, ek[3].y, a);
                acc[r][1] = a;
                a = acc[r][2];
                a = fmaf(zv.x, ek[0].z, a); a = fmaf(zv.y, ek[1].z, a);
                a = fmaf(zv.z, ek[2].z, a); a = fmaf(zv.w, ek[3].z, a);
                acc[r][2] = a;
                a = acc[r][3];
                a = fmaf(zv.x, ek[0].w, a); a = fmaf(zv.y, ek[1].w, a);
                a = fmaf(zv.z, ek[2].w, a); a = fmaf(zv.w, ek[3].w, a);
                acc[r][3] = a;
            }
        }
        float esql[4];
#pragma unroll
        for (int j = 0; j < 4; ++j) esql[j] = esq[kbase + j];
#pragma unroll
        for (int r = 0; r < 8; ++r) {
            int n = nrow[r];
            float xs = (n >= 0) ? xsq[n] : 0.0f;
            float m = 3.4e38f;
            int mi = 0;
#pragma unroll
            for (int j = 0; j < 4; ++j) {
                float t1 = xs + esql[j];
                float d = t1 - 2.0f * acc[r][j];
                if (d < m) { m = d; mi = kbase + j; }
            }
            unsigned long long p = ((unsigned long long)__float_as_uint(m) << 32) | (unsigned)mi;
            for (int off = 32; off >= 1; off >>= 1) {
                unsigned long long o = __shfl_xor(p, off, 64);
                p = (o < p) ? o : p;
            }
            if ((tid & 63) == 0) red[r][tid >> 6] = p;
        }
        __syncthreads();
        if (tid < 8 && nrow[tid] >= 0) {
            unsigned long long p = red[tid][0];
#pragma unroll
            for (int ww = 1; ww < 4; ++ww) { unsigned long long o = red[tid][ww]; p = (o < p) ? o : p; }
            int idx = (int)(p & 0xFFFFFFFFull);
            out_idx[nrow[tid]] = (float)idx;
            atomicAdd(&counts[idx], 1u);
        }
    }
}

// ---------- gather + losses (validated) ----------

__global__ __launch_bounds__(256) void gather_kernel(
    const float* __restrict__ z, const float* __restrict__ embT,
    const float* __restrict__ out_idx, float* __restrict__ out,
    double* __restrict__ loss_acc) {
    const int tid = threadIdx.x;
    const int ct = blockIdx.x & 3;
    const int st = (blockIdx.x >> 2) & 15;
    const int b  = blockIdx.x >> 6;
    const int s0 = st * 1024;
    const int c0 = ct * 64;

    int idx[4];
#pragma unroll
    for (int q = 0; q < 4; ++q)
        idx[q] = (int)out_idx[(b << 14) + s0 + 4 * tid + q];

    const float* zb = z + ((size_t)b << 22) + s0 + 4 * tid;
    float* ob = out + ((size_t)b << 22) + s0 + 4 * tid;

    double local = 0.0;
    for (int c = 0; c < 64; ++c) {
        const int cg = c0 + c;
        const float* er = embT + (size_t)cg * K_CODES;
        float4 zv = *reinterpret_cast<const float4*>(zb + ((size_t)cg << 14));
        float4 ov;
        float d0 = er[idx[0]] - zv.x;
        float d1 = er[idx[1]] - zv.y;
        float d2 = er[idx[2]] - zv.z;
        float d3 = er[idx[3]] - zv.w;
        ov.x = zv.x + d0; ov.y = zv.y + d1; ov.z = zv.z + d2; ov.w = zv.w + d3;
        *reinterpret_cast<float4*>(ob + ((size_t)cg << 14)) = ov;
        local += (double)d0 * d0 + (double)d1 * d1 + (double)d2 * d2 + (double)d3 * d3;
    }
    for (int off = 32; off >= 1; off >>= 1) local += __shfl_down(local, off, 64);
    __shared__ double redd[4];
    if ((tid & 63) == 0) redd[tid >> 6] = local;
    __syncthreads();
    if (tid == 0) atomicAdd(loss_acc, redd[0] + redd[1] + redd[2] + redd[3]);
}

__global__ void finalize_kernel(const unsigned* __restrict__ counts,
                                const double* __restrict__ loss_acc,
                                float* __restrict__ out) {
    int tid = threadIdx.x;
    double s = 0.0;
    for (int k = tid; k < K_CODES; k += 256) {
        float avg = (float)counts[k] / 65536.0f;
        float t = avg * logf(avg + 1e-10f);
        s += (double)t;
    }
    for (int off = 32; off >= 1; off >>= 1) s += __shfl_down(s, off, 64);
    __shared__ double red[4];
    if ((tid & 63) == 0) red[tid >> 6] = s;
    __syncthreads();
    if (tid == 0) {
        double tot = red[0] + red[1] + red[2] + red[3];
        out[OUT_PP_OFF]   = expf((float)(-tot));
        out[OUT_LOSS_OFF] = 1.25f * (float)(loss_acc[0] / 16777216.0);
    }
}

extern "C" void kernel_launch(void* const* d_in, const int* in_sizes, int n_in,
                              void* d_out, int out_size, void* d_ws, size_t ws_size,
                              hipStream_t stream) {
    const float* z   = (const float*)d_in[0];
    const float* emb = (const float*)d_in[1];
    float* out = (float*)d_out;
    char* ws = (char*)d_ws;

    unsigned short* ehF = (unsigned short*)(ws + WS_EH);
    unsigned short* elF = (unsigned short*)(ws + WS_EL);
    float*    esq       = (float*)(ws + WS_ESQ);
    float*    xsq       = (float*)(ws + WS_XSQ);
    unsigned* counts    = (unsigned*)(ws + WS_CNT);
    double*   loss_acc  = (double*)(ws + WS_LOSS);
    unsigned* flag_cnt  = (unsigned*)(ws + WS_FLC);
    unsigned* flist     = (unsigned*)(ws + WS_FLIST);
    float*    embT      = (float*)(ws + WS_EMBT);

    unsigned short* zhF = (unsigned short*)out;                // [0, 33.5 MB)
    float*    pmA   = out + 8388608;                           // f32[64][65536]
    unsigned* packd = (unsigned*)(out + 8388608 + 4194304);    // u32[64][65536]
    float* out_idx = out + OUT_IDX_OFF;

    hipMemsetAsync(ws + WS_CNT, 0, 4108, stream);   // counts + loss + flag_count

    convert_z_kernel<<<1024, 256, 0, stream>>>(z, zhF, xsq);
    convert_e_kernel<<<128, 256, 0, stream>>>(emb, ehF, elF, esq);
    screen_kernel<<<1024, 256, 0, stream>>>(zhF, ehF, elF, esq, pmA, packd);
    merge_kernel<<<256, 256, 0, stream>>>(pmA, packd, flist, flag_cnt, out_idx, counts);
    transpose_kernel<<<dim3(16, 4), 256, 0, stream>>>(emb, embT);
    refine_kernel<<<1024, 256, 0, stream>>>(z, embT, esq, xsq, flist, flag_cnt, out_idx, counts);
    gather_kernel<<<256, 256, 0, stream>>>(z, embT, out_idx, out, loss_acc);
    finalize_kernel<<<1, 256, 0, stream>>>(counts, loss_acc, out);
}

// Round 19
// 239.924 us; speedup vs baseline: 1.3733x; 1.3733x over previous
//
#include <hip/hip_runtime.h>

// VQ-VAE vector quantizer, MI355X — MFMA screen ((eh+el)*zh, 4 acc chains,
// zh-only LDS staging; r14-validated, best-measured 108us) + exact refine.
// z: (4,256,16,32,32) f32 ; emb: (1024,256) f32
// out (f32): z_q_st[16777216] | vq_loss | perplexity | indices[65536]
//
// Exactness contract (validated rounds 2-18, absmax 0):
//   x_sq[n], e_sq[k]: numpy pairwise sum of fl32(v*v) (two 128-blocks, 8 accs)
//   xe[n][k]: single sequential f32 FMA chain over c=0..255
//   d = fl32( fl32(x_sq+e_sq) - 2*xe ), argmin first-min tie-break.
// Screen = bf16-split MFMA eh*zh + el*zh; T_GAP=6e-4 flags rows for the
// bit-exact scalar-chain refine (validated r14).
//
// Round-19 (consolidation): r12-r18 ledger: MFMA-busy always at instruction
// floor; util capped 17-38% by register-footprint occupancy (E-resident =
// ~190 unified regs/wave -> 2 waves/SIMD). r14's screen (108us) is the best
// of 7 structural variants; revert to it verbatim. Tail trims: wave-aggregated
// flag compaction in merge (1 atomic/wave vs per-thread same-address atomics);
// transpose launched early.

#define C_DIM 256
#define K_CODES 1024
#define N_VEC 65536
#define T_GAP 6e-4f

#define OUT_ZQ_SIZE 16777216
#define OUT_LOSS_OFF 16777216
#define OUT_PP_OFF   16777217
#define OUT_IDX_OFF  16777218

// ws layout (bytes)
#define WS_EH    0          // bf16 frag-major [32 kt][16 q][64 l][8]   512 KB
#define WS_EL    524288     // same                                     512 KB
#define WS_ESQ   1048576    // f32 [1024]
#define WS_XSQ   1052672    // f32 [65536]
#define WS_CNT   1314816    // u32 counts[1024]
#define WS_LOSS  1318912    // f64 loss
#define WS_FLC   1318920    // u32 flag count
#define WS_FLIST 1581072    // u32 flag_list[65536]
#define WS_PM1   1843264    // f32 [4][65536]
#define WS_EMBT  1843264    // f32 [256][1024] (overlays PM1 after merge)
#define WS_PM2   2891840    // f32 [4][65536]
#define WS_PIX   3940416    // u16 [4][65536]  (ends 4464704)

typedef __attribute__((ext_vector_type(8))) short short8;
typedef __attribute__((ext_vector_type(8))) unsigned short ushort8;
typedef __attribute__((ext_vector_type(16))) float f32x16;

__device__ __forceinline__ unsigned short bf16_rne(float v) {
    unsigned u = __float_as_uint(v);
    unsigned r = (u + 0x7FFFu + ((u >> 16) & 1u)) >> 16;
    return (unsigned short)r;
}

// fragment-major address (in shorts) of element (row, c) within a panel:
//   tile = row>>5, q = c>>4, lane = (row&31) + 32*((c>>3)&1), j = c&7
//   off  = tile*8192 + q*512 + lane*8 + j

// ---------- conversions (xsq fused into convert_z; esq fused into convert_e) ----------

__global__ __launch_bounds__(256) void convert_z_kernel(const float* __restrict__ z,
                                                        unsigned short* __restrict__ zhF,
                                                        float* __restrict__ xsq) {
#pragma clang fp contract(off)
    __shared__ float tile[128][65];
    const int tid = threadIdx.x;
    const int ln = tid & 63;
    const int og = tid >> 6;
    const int n0 = blockIdx.x * 64;
    const int b = n0 >> 14, s0 = n0 & 16383;
    const int n = n0 + ln;
    const size_t tbase = (size_t)(n >> 5) * 8192;
    const int lr = n & 31;
    float res = 0.0f;

    for (int p = 0; p < 2; ++p) {
        __syncthreads();
        for (int i = 0; i < 32; ++i) {
            int c = p * 128 + i * 4 + og;
            tile[i * 4 + og][ln] = z[((size_t)b << 22) + ((size_t)c << 14) + s0 + ln];
        }
        __syncthreads();
        // frag-major bf16 writes (4 c-octets per thread in this half)
#pragma unroll
        for (int t = 0; t < 4; ++t) {
            int oh = og + t * 4;               // octet within half, 0..15
            int o  = p * 16 + oh;              // global c-octet 0..31
            ushort8 hb;
#pragma unroll
            for (int j = 0; j < 8; ++j)
                hb[j] = bf16_rne(tile[oh * 8 + j][ln]);
            size_t off = tbase + (size_t)(o >> 1) * 512 + (size_t)(lr + 32 * (o & 1)) * 8;
            *reinterpret_cast<ushort8*>(zhF + off) = hb;
        }
        // numpy pairwise 128-block for this c-half (strided LDS reads, exact order)
        if (tid < 64) {
            float r[8];
#pragma unroll
            for (int j = 0; j < 8; ++j) { float v = tile[j][tid]; r[j] = v * v; }
#pragma unroll
            for (int i = 8; i < 128; i += 8)
#pragma unroll
                for (int j = 0; j < 8; ++j) { float v = tile[i + j][tid]; float t2 = v * v; r[j] = r[j] + t2; }
            float blk = ((r[0] + r[1]) + (r[2] + r[3])) + ((r[4] + r[5]) + (r[6] + r[7]));
            res = (p == 0) ? blk : res + blk;
        }
    }
    if (tid < 64) xsq[n0 + tid] = res;
}

__device__ __forceinline__ float pairwise_sq_128(const float* p) {
#pragma clang fp contract(off)
    float r[8];
#pragma unroll
    for (int j = 0; j < 8; ++j) { float v = p[j]; r[j] = v * v; }
#pragma unroll
    for (int i = 8; i < 128; i += 8)
#pragma unroll
        for (int j = 0; j < 8; ++j) { float v = p[i + j]; float t = v * v; r[j] = r[j] + t; }
    return ((r[0] + r[1]) + (r[2] + r[3])) + ((r[4] + r[5]) + (r[6] + r[7]));
}

__global__ __launch_bounds__(256) void convert_e_kernel(const float* __restrict__ emb,
                                                        unsigned short* __restrict__ ehF,
                                                        unsigned short* __restrict__ elF,
                                                        float* __restrict__ esq) {
#pragma clang fp contract(off)
    int t = blockIdx.x * 256 + threadIdx.x;   // 32768 threads
    int k = t >> 5, o = t & 31;
    int c0 = o * 8;
    ushort8 hb, lb;
#pragma unroll
    for (int j = 0; j < 8; ++j) {
        float v = emb[k * C_DIM + c0 + j];
        unsigned short h = bf16_rne(v);
        hb[j] = h;
        lb[j] = bf16_rne(v - __uint_as_float((unsigned)h << 16));
    }
    size_t off = (size_t)(k >> 5) * 8192 + (size_t)(o >> 1) * 512 + (size_t)((k & 31) + 32 * (o & 1)) * 8;
    *reinterpret_cast<ushort8*>(ehF + off) = hb;
    *reinterpret_cast<ushort8*>(elF + off) = lb;
    // esq for this block's 8 k-rows (L1-hot), exact numpy pairwise
    if (threadIdx.x < 8) {
        int k8 = blockIdx.x * 8 + threadIdx.x;
        const float* row = emb + (size_t)k8 * C_DIM;
        esq[k8] = pairwise_sq_128(row) + pairwise_sq_128(row + 128);
    }
}

__global__ __launch_bounds__(256) void transpose_kernel(const float* __restrict__ emb,
                                                        float* __restrict__ embT) {
    __shared__ float t[64][65];
    const int k0 = blockIdx.x * 64;
    const int c0 = blockIdx.y * 64;
    const int tx = threadIdx.x & 63, ty = threadIdx.x >> 6;
    for (int r = ty; r < 64; r += 4)
        t[r][tx] = emb[(k0 + r) * C_DIM + c0 + tx];
    __syncthreads();
    for (int r = ty; r < 64; r += 4)
        embT[(c0 + r) * K_CODES + k0 + tx] = t[tx][r];
}

// ---------- MFMA screen: E-in-registers (A-operand), zh-streamed (B-operand) ----------
// block: 512 threads = 8 waves; block covers 512n x 256k; grid 512 = 128 nb x 4 kb.
// Per q: 2 A-reads, 4 MFMAs into 4 INDEPENDENT chains (dep-latency cover).
// r14-validated (108us, absmax 0).

__global__ __launch_bounds__(512, 1) void screen_kernel(
    const unsigned short* __restrict__ zhF,
    const unsigned short* __restrict__ ehF, const unsigned short* __restrict__ elF,
    const float* __restrict__ esq, const float* __restrict__ xsq,
    float* __restrict__ pm1, float* __restrict__ pm2,
    unsigned short* __restrict__ pix) {
    __shared__ __align__(16) unsigned short abuf[2][32 * 512];   // 64 KB, double buffer
    __shared__ float xbuf[512];
    __shared__ float smp1[2][8][64], smp2[2][8][64];
    __shared__ int   smi[2][8][64];

    const int tid = threadIdx.x;
    const int w = tid >> 6, l = tid & 63, lr = l & 31, lh = l >> 5;
    const int bid = blockIdx.x;
    const int v = (bid & 7) * 64 + (bid >> 3);   // XCD-chunked bijective swizzle (512 = 8*64)
    const int nb = v >> 2, kb = v & 3;
    const int n0 = nb * 512;
    const int kw = kb * 256 + w * 32;            // this wave's 32-k strip
    const int loff = l * 8;

    // ---- resident E (A-operand): one frag-major 32-k tile per wave, high+low ----
    short8 Eh[16], El[16];
    {
        const unsigned short* bh = ehF + (size_t)(kb * 8 + w) * 8192 + loff;
        const unsigned short* bl = elF + (size_t)(kb * 8 + w) * 8192 + loff;
#pragma unroll
        for (int q = 0; q < 16; ++q) {
            Eh[q] = *reinterpret_cast<const short8*>(bh + q * 512);
            El[q] = *reinterpret_cast<const short8*>(bl + q * 512);
        }
    }
    // per-lane e_sq for the 16 k-rows this lane sees (k = kw + crow(r,lh))
    float esql[16];
#pragma unroll
    for (int r = 0; r < 16; ++r)
        esql[r] = esq[kw + (r & 3) + 8 * (r >> 2) + 4 * lh];

    // xsq for the block's 512 n -> LDS (4B DMA per lane)
    __builtin_amdgcn_global_load_lds(
        (const __attribute__((address_space(1))) void*)(xsq + n0 + w * 64 + l),
        (__attribute__((address_space(3))) void*)&xbuf[w * 64], 4, 0, 0);

    asm volatile("s_waitcnt vmcnt(0)" ::: "memory");   // drain E + xbuf
    __builtin_amdgcn_s_barrier();

    // ---- A staging: window s = 64n of zh; chunks 0-15 tile0 q0-15, 16-31 tile1 ----
#define STAGE(S) do {                                                                   \
    const int _b = (S) & 1;                                                             \
    _Pragma("unroll")                                                                   \
    for (int ci = 0; ci < 4; ++ci) {                                                    \
        int c = 4 * w + ci;                                                             \
        const unsigned short* src = zhF                                                 \
            + (size_t)((n0 >> 5) + (S) * 2 + (c >> 4)) * 8192                           \
            + (size_t)(c & 15) * 512 + loff;                                            \
        __builtin_amdgcn_global_load_lds(                                               \
            (const __attribute__((address_space(1))) void*)src,                         \
            (__attribute__((address_space(3))) void*)&abuf[_b][c * 512], 16, 0, 0);     \
    }                                                                                   \
} while (0)

    STAGE(0);

    float rm1 = 3.4e38f, rm2 = 3.4e38f;   // this wave's merged result (window s == w)
    int   ri1 = 0;

    for (int s = 0; s < 8; ++s) {
        const int cur = s & 1;
        // depth-1: my 4 STAGE(s) loads are the only outstanding DMAs.
        // lgkmcnt(0) publishes the previous step's fold writes before the barrier.
        asm volatile("s_waitcnt vmcnt(0) lgkmcnt(0)" ::: "memory");
        __builtin_amdgcn_s_barrier();
        __builtin_amdgcn_sched_barrier(0);
        if (s < 7) STAGE(s + 1);   // into buffer cur^1: consumed last step by everyone

        // deferred merge of window s-1 (parity (s-1)&1), by wave s-1
        if (s >= 1 && w == s - 1) {
            const int pp = (s - 1) & 1;
            float m1 = smp1[pp][0][l], m2 = smp2[pp][0][l];
            int i1 = smi[pp][0][l];
#pragma unroll
            for (int ww = 1; ww < 8; ++ww) {
                float q1 = smp1[pp][ww][l], q2 = smp2[pp][ww][l];
                int qi = smi[pp][ww][l];
                if (q1 < m1)      { m2 = fminf(m1, q2); m1 = q1; i1 = qi; }
                else if (q1 > m1) { m2 = fminf(m2, q1); }
                else              { m2 = m1; }   // ww ascending = k ascending
            }
            rm1 = m1; rm2 = m2; ri1 = i1;
        }

        // 4 independent accumulator chains (cover MFMA dependent latency)
        f32x16 aH0, aL0, aH1, aL1;
#pragma unroll
        for (int r = 0; r < 16; ++r) { aH0[r] = 0.0f; aL0[r] = 0.0f; aH1[r] = 0.0f; aL1[r] = 0.0f; }

        __builtin_amdgcn_s_setprio(1);
#pragma unroll
        for (int q = 0; q < 16; ++q) {
            short8 azh0 = *reinterpret_cast<const short8*>(&abuf[cur][(q)      * 512 + loff]);
            short8 azh1 = *reinterpret_cast<const short8*>(&abuf[cur][(16 + q) * 512 + loff]);
            aH0 = __builtin_amdgcn_mfma_f32_32x32x16_bf16(Eh[q], azh0, aH0, 0, 0, 0);
            aL0 = __builtin_amdgcn_mfma_f32_32x32x16_bf16(El[q], azh0, aL0, 0, 0, 0);
            aH1 = __builtin_amdgcn_mfma_f32_32x32x16_bf16(Eh[q], azh1, aH1, 0, 0, 0);
            aL1 = __builtin_amdgcn_mfma_f32_32x32x16_bf16(El[q], azh1, aL1, 0, 0, 0);
        }
        __builtin_amdgcn_s_setprio(0);

        // fold: lane's col n = lr (per tile); 16 k-rows live in acc registers
#pragma unroll
        for (int i = 0; i < 2; ++i) {
            const f32x16 aH = i ? aH1 : aH0;
            const f32x16 aL = i ? aL1 : aL0;
            const float xs = xbuf[s * 64 + i * 32 + lr];
            float m1 = 3.4e38f, m2 = 3.4e38f;
            int i1 = 0;
#pragma unroll
            for (int r = 0; r < 16; ++r) {            // kg ascending in r
                float dot = aH[r] + aL[r];
                float sv = (xs + esql[r]) - 2.0f * dot;
                int kg = kw + (r & 3) + 8 * (r >> 2) + 4 * lh;
                if (sv < m1) { m2 = m1; m1 = sv; i1 = kg; }
                else m2 = fminf(m2, sv);
            }
            // merge lh halves (disjoint k sets for same n)
            float om1 = __shfl_xor(m1, 32, 64);
            float om2 = __shfl_xor(m2, 32, 64);
            int   oi  = __shfl_xor(i1, 32, 64);
            if (om1 < m1)      { m2 = fminf(m1, om2); m1 = om1; i1 = oi; }
            else if (om1 > m1) { m2 = fminf(m2, om1); }
            else               { m2 = m1; i1 = min(i1, oi); }
            if (lh == 0) {
                smp1[s & 1][w][i * 32 + lr] = m1;
                smp2[s & 1][w][i * 32 + lr] = m2;
                smi [s & 1][w][i * 32 + lr] = i1;
            }
        }
        // no second barrier: next step's top lgkmcnt(0)+barrier publishes smp
    }
#undef STAGE

    asm volatile("s_waitcnt lgkmcnt(0)" ::: "memory");
    __builtin_amdgcn_s_barrier();
    if (w == 7) {   // merge window 7 (parity 1)
        float m1 = smp1[1][0][l], m2 = smp2[1][0][l];
        int i1 = smi[1][0][l];
#pragma unroll
        for (int ww = 1; ww < 8; ++ww) {
            float q1 = smp1[1][ww][l], q2 = smp2[1][ww][l];
            int qi = smi[1][ww][l];
            if (q1 < m1)      { m2 = fminf(m1, q2); m1 = q1; i1 = qi; }
            else if (q1 > m1) { m2 = fminf(m2, q1); }
            else              { m2 = m1; }
        }
        rm1 = m1; rm2 = m2; ri1 = i1;
    }

    // wave w owns window s==w: n = n0 + w*64 + l
    {
        size_t p = (size_t)kb * N_VEC + n0 + w * 64 + l;
        pm1[p] = rm1; pm2[p] = rm2; pix[p] = (unsigned short)ri1;
    }
}

// merge + emit fused: unflagged rows finalized here; flagged rows -> refine.
// Flag compaction is wave-aggregated (1 atomic per wave); list order is
// non-deterministic across waves but refine is order-independent.
__global__ __launch_bounds__(256) void merge_kernel(
    const float* __restrict__ pm1, const float* __restrict__ pm2,
    const unsigned short* __restrict__ pix,
    unsigned* __restrict__ flag_list, unsigned* __restrict__ flag_count,
    float* __restrict__ out_idx, unsigned* __restrict__ counts) {
    int n = blockIdx.x * 256 + threadIdx.x;
    const int lane = threadIdx.x & 63;
    float m1 = 3.4e38f, m2 = 3.4e38f;
    int i1 = 0;
    for (int kb = 0; kb < 4; ++kb) {
        size_t p = (size_t)kb * N_VEC + n;
        float a1 = pm1[p], a2 = pm2[p];
        int ai = (int)pix[p];
        if (a1 < m1)      { m2 = fminf(m1, a2); m1 = a1; i1 = ai; }
        else if (a1 > m1) { m2 = fminf(m2, a1); }
        else              { m2 = m1; i1 = min(i1, ai); }
    }
    bool flag = (m2 - m1 <= T_GAP);
    unsigned long long mask = __ballot(flag);
    if (flag) {
        int leader = __ffsll((long long)mask) - 1;
        int rank = __popcll(mask & ((lane == 0) ? 0ull : ((~0ull) >> (64 - lane))));
        unsigned base = 0;
        if (lane == leader) base = atomicAdd(flag_count, (unsigned)__popcll(mask));
        base = __shfl(base, leader, 64);
        flag_list[base + rank] = (unsigned)n;
    } else {
        out_idx[n] = (float)i1;
        atomicAdd(&counts[i1], 1u);
    }
}

// ---------- exact-chain refine of flagged rows (8 rows/group) ----------

__global__ __launch_bounds__(256) void refine_kernel(
    const float* __restrict__ z, const float* __restrict__ embT,
    const float* __restrict__ esq, const float* __restrict__ xsq,
    const unsigned* __restrict__ flag_list, const unsigned* __restrict__ flag_count,
    float* __restrict__ out_idx, unsigned* __restrict__ counts) {
#pragma clang fp contract(off)
    __shared__ float zrow[8][256];
    __shared__ int nrow[8];
    __shared__ unsigned long long red[8][4];
    const int tid = threadIdx.x;
    const unsigned cnt = *flag_count;
    const unsigned groups = (cnt + 7) >> 3;
    const int kbase = tid * 4;
    for (unsigned g = blockIdx.x; g < groups; g += gridDim.x) {
        __syncthreads();
        if (tid < 8) nrow[tid] = (g * 8 + tid < cnt) ? (int)flag_list[g * 8 + tid] : -1;
        __syncthreads();
        for (int r = 0; r < 8; ++r) {
            int n = nrow[r];
            if (n >= 0) {
                int b = n >> 14, s = n & 16383;
                zrow[r][tid] = z[((size_t)b << 22) + ((size_t)tid << 14) + s];
            }
        }
        __syncthreads();
        float acc[8][4];
#pragma unroll
        for (int r = 0; r < 8; ++r)
#pragma unroll
            for (int j = 0; j < 4; ++j) acc[r][j] = 0.0f;
        for (int c4 = 0; c4 < 64; ++c4) {
            float4 ek[4];
#pragma unroll
            for (int x = 0; x < 4; ++x)
                ek[x] = *reinterpret_cast<const float4*>(embT + (size_t)(c4 * 4 + x) * K_CODES + kbase);
#pragma unroll
            for (int r = 0; r < 8; ++r) {
                float4 zv = *reinterpret_cast<const float4*>(&zrow[r][c4 * 4]);
                float a;
                a = acc[r][0];
                a = fmaf(zv.x, ek[0].x, a); a = fmaf(zv.y, ek[1].x, a);
                a = fmaf(zv.z, ek[2].x, a); a = fmaf(zv.w, ek[3].x, a);
                acc[r][0] = a;
                a = acc[r][1];
                a = fmaf(zv.x, ek[0].y, a); a = fmaf(zv.y, ek[1].y, a);
                a = fmaf(zv.z, ek[2].y, a); a = fmaf(zv.w, ek[3].y, a);
                acc[r][1] = a;
                a = acc[r][2];
                a = fmaf(zv.x, ek[0].z, a); a = fmaf(zv.y, ek[1].z, a);
                a = fmaf(zv.z, ek[2].z, a); a = fmaf(zv.w, ek[3].z, a);
                acc[r][2] = a;
                a = acc[r][3];
                a = fmaf(zv.x, ek[0].w, a); a = fmaf(zv.y, ek[1].w, a);
                a = fmaf(zv.z, ek[2].w, a); a = fmaf(zv.w, ek[3].w, a);
                acc[r][3] = a;
            }
        }
        float esql[4];
#pragma unroll
        for (int j = 0; j < 4; ++j) esql[j] = esq[kbase + j];
#pragma unroll
        for (int r = 0; r < 8; ++r) {
            int n = nrow[r];
            float xs = (n >= 0) ? xsq[n] : 0.0f;
            float m = 3.4e38f;
            int mi = 0;
#pragma unroll
            for (int j = 0; j < 4; ++j) {
                float t1 = xs + esql[j];
                float d = t1 - 2.0f * acc[r][j];
                if (d < m) { m = d; mi = kbase + j; }
            }
            unsigned long long p = ((unsigned long long)__float_as_uint(m) << 32) | (unsigned)mi;
            for (int off = 32; off >= 1; off >>= 1) {
                unsigned long long o = __shfl_xor(p, off, 64);
                p = (o < p) ? o : p;
            }
            if ((tid & 63) == 0) red[r][tid >> 6] = p;
        }
        __syncthreads();
        if (tid < 8 && nrow[tid] >= 0) {
            unsigned long long p = red[tid][0];
#pragma unroll
            for (int ww = 1; ww < 4; ++ww) { unsigned long long o = red[tid][ww]; p = (o < p) ? o : p; }
            int idx = (int)(p & 0xFFFFFFFFull);
            out_idx[nrow[tid]] = (float)idx;
            atomicAdd(&counts[idx], 1u);
        }
    }
}

// ---------- gather + losses (validated) ----------

__global__ __launch_bounds__(256) void gather_kernel(
    const float* __restrict__ z, const float* __restrict__ embT,
    const float* __restrict__ out_idx, float* __restrict__ out,
    double* __restrict__ loss_acc) {
    const int tid = threadIdx.x;
    const int ct = blockIdx.x & 3;
    const int st = (blockIdx.x >> 2) & 15;
    const int b  = blockIdx.x >> 6;
    const int s0 = st * 1024;
    const int c0 = ct * 64;

    int idx[4];
#pragma unroll
    for (int q = 0; q < 4; ++q)
        idx[q] = (int)out_idx[(b << 14) + s0 + 4 * tid + q];

    const float* zb = z + ((size_t)b << 22) + s0 + 4 * tid;
    float* ob = out + ((size_t)b << 22) + s0 + 4 * tid;

    double local = 0.0;
    for (int c = 0; c < 64; ++c) {
        const int cg = c0 + c;
        const float* er = embT + (size_t)cg * K_CODES;
        float4 zv = *reinterpret_cast<const float4*>(zb + ((size_t)cg << 14));
        float4 ov;
        float d0 = er[idx[0]] - zv.x;
        float d1 = er[idx[1]] - zv.y;
        float d2 = er[idx[2]] - zv.z;
        float d3 = er[idx[3]] - zv.w;
        ov.x = zv.x + d0; ov.y = zv.y + d1; ov.z = zv.z + d2; ov.w = zv.w + d3;
        *reinterpret_cast<float4*>(ob + ((size_t)cg << 14)) = ov;
        local += (double)d0 * d0 + (double)d1 * d1 + (double)d2 * d2 + (double)d3 * d3;
    }
    for (int off = 32; off >= 1; off >>= 1) local += __shfl_down(local, off, 64);
    __shared__ double redd[4];
    if ((tid & 63) == 0) redd[tid >> 6] = local;
    __syncthreads();
    if (tid == 0) atomicAdd(loss_acc, redd[0] + redd[1] + redd[2] + redd[3]);
}

__global__ void finalize_kernel(const unsigned* __restrict__ counts,
                                const double* __restrict__ loss_acc,
                                float* __restrict__ out) {
    int tid = threadIdx.x;
    double s = 0.0;
    for (int k = tid; k < K_CODES; k += 256) {
        float avg = (float)counts[k] / 65536.0f;
        float t = avg * logf(avg + 1e-10f);
        s += (double)t;
    }
    for (int off = 32; off >= 1; off >>= 1) s += __shfl_down(s, off, 64);
    __shared__ double red[4];
    if ((tid & 63) == 0) red[tid >> 6] = s;
    __syncthreads();
    if (tid == 0) {
        double tot = red[0] + red[1] + red[2] + red[3];
        out[OUT_PP_OFF]   = expf((float)(-tot));
        out[OUT_LOSS_OFF] = 1.25f * (float)(loss_acc[0] / 16777216.0);
    }
}

extern "C" void kernel_launch(void* const* d_in, const int* in_sizes, int n_in,
                              void* d_out, int out_size, void* d_ws, size_t ws_size,
                              hipStream_t stream) {
    const float* z   = (const float*)d_in[0];
    const float* emb = (const float*)d_in[1];
    float* out = (float*)d_out;
    char* ws = (char*)d_ws;

    unsigned short* ehF = (unsigned short*)(ws + WS_EH);
    unsigned short* elF = (unsigned short*)(ws + WS_EL);
    float*    esq       = (float*)(ws + WS_ESQ);
    float*    xsq       = (float*)(ws + WS_XSQ);
    unsigned* counts    = (unsigned*)(ws + WS_CNT);
    double*   loss_acc  = (double*)(ws + WS_LOSS);
    unsigned* flag_cnt  = (unsigned*)(ws + WS_FLC);
    unsigned* flist     = (unsigned*)(ws + WS_FLIST);
    float*    pm1       = (float*)(ws + WS_PM1);
    float*    pm2       = (float*)(ws + WS_PM2);
    unsigned short* pix = (unsigned short*)(ws + WS_PIX);
    float*    embT      = (float*)(ws + WS_EMBT);

    unsigned short* zhF = (unsigned short*)out;                // [0, 33.5 MB)
    float* out_idx = out + OUT_IDX_OFF;

    hipMemsetAsync(ws + WS_CNT, 0, 4108, stream);   // counts + loss + flag_count

    convert_z_kernel<<<1024, 256, 0, stream>>>(z, zhF, xsq);
    convert_e_kernel<<<128, 256, 0, stream>>>(emb, ehF, elF, esq);
    screen_kernel<<<512, 512, 0, stream>>>(zhF, ehF, elF, esq, xsq, pm1, pm2, pix);
    merge_kernel<<<256, 256, 0, stream>>>(pm1, pm2, pix, flist, flag_cnt, out_idx, counts);
    transpose_kernel<<<dim3(16, 4), 256, 0, stream>>>(emb, embT);   // embT overlays pm1
    refine_kernel<<<1024, 256, 0, stream>>>(z, embT, esq, xsq, flist, flag_cnt, out_idx, counts);
    gather_kernel<<<256, 256, 0, stream>>>(z, embT, out_idx, out, loss_acc);
    finalize_kernel<<<1, 256, 0, stream>>>(counts, loss_acc, out);
}